// Round 12
// baseline (158.178 us; speedup 1.0000x reference)
//
#include <hip/hip_runtime.h>

typedef unsigned short u16;
typedef unsigned int u32;
typedef __bf16 bf16x8 __attribute__((ext_vector_type(8)));
typedef float f32x4 __attribute__((ext_vector_type(4)));
typedef float f32x16 __attribute__((ext_vector_type(16)));
typedef u16 u16x8 __attribute__((ext_vector_type(8)));
typedef u32 u32x2 __attribute__((ext_vector_type(2)));
typedef u32 u32x4 __attribute__((ext_vector_type(4)));

#define MFMA16(a, b, c) __builtin_amdgcn_mfma_f32_16x16x32_bf16((a), (b), (c), 0, 0, 0)
#define MFMA32(a, b, c) __builtin_amdgcn_mfma_f32_32x32x16_bf16((a), (b), (c), 0, 0, 0)

__device__ __forceinline__ u16 f2bf(float f) {
    unsigned int u = __float_as_uint(f);
    u = (u + 0x7FFF + ((u >> 16) & 1)) >> 16;
    return (u16)u;
}

__device__ __forceinline__ u32 cvtpk(float a, float b) {
    u32 d;
    asm("v_cvt_pk_bf16_f32 %0, %1, %2" : "=v"(d) : "v"(a), "v"(b));
    return d;
}

__device__ __forceinline__ void gld_lds16(const u16* g, u16* l) {
    __builtin_amdgcn_global_load_lds(
        (const __attribute__((address_space(1))) unsigned int*)g,
        (__attribute__((address_space(3))) unsigned int*)l, 16, 0, 0);
}

// ---------------- fp32 -> bf16 cast ----------------
__global__ __launch_bounds__(256) void cvt_bf16(const float* __restrict__ in,
                                                u16* __restrict__ out, int n4) {
    int idx = blockIdx.x * blockDim.x + threadIdx.x;
    int stride = gridDim.x * blockDim.x;
    for (int i = idx; i < n4; i += stride) {
        float4 v = reinterpret_cast<const float4*>(in)[i];
        ushort4 o;
        o.x = f2bf(v.x); o.y = f2bf(v.y); o.z = f2bf(v.z); o.w = f2bf(v.w);
        reinterpret_cast<ushort4*>(out)[i] = o;
    }
}

// ---------------- partial-sum reduce: o = a + b ----------------
__global__ __launch_bounds__(256) void reduce_add(const float4* __restrict__ a,
                                                  const float4* __restrict__ b,
                                                  float4* __restrict__ o, int n4) {
    int idx = blockIdx.x * blockDim.x + threadIdx.x;
    int stride = gridDim.x * blockDim.x;
    for (int i = idx; i < n4; i += stride) {
        float4 va = a[i], vb = b[i];
        float4 vo = {va.x + vb.x, va.y + vb.y, va.z + vb.z, va.w + vb.w};
        o[i] = vo;
    }
}

// ---- bf16 GEMM: BARRIER-FREE per-wave-private staging, depth-3 counted vmcnt ----
// 4 waves; wave (wr,wc)=(w>>1,w&1) owns a 64x64 quadrant of the 128^2 tile and
// stages its OWN A/B 64x32 panels into a private 24KB LDS slice (3 buffers).
// No s_barrier in the K-loop: waves free-run; per-wave vmcnt(16) keeps 2 tiles
// in flight. LDS swizzle identical to r11's PMC-verified conflict-free pattern.
template <int SPLITK>
__global__ __launch_bounds__(256) void gemm_bt(const u16* __restrict__ A,
                                               const u16* __restrict__ B,
                                               float* __restrict__ C,
                                               int M, int N, int K) {
    __shared__ __align__(16) u16 lds[4][3][4096];  // [wave][buf][A 2048 | B 2048] = 96KB

    int nbn = N >> 7;
    int bid = blockIdx.x;
    int nwg = (M >> 7) * nbn;
    int cpx = nwg >> 3;
    int wg = (bid & 7) * cpx + (bid >> 3);   // XCD swizzle (gridX % 8 == 0)
    int tm = wg / nbn, tn = wg % nbn;
    int m0 = tm << 7, n0 = tn << 7;

    int Ks = K / SPLITK;
    int kbase = blockIdx.y * Ks;
    float* Cs = C + (size_t)blockIdx.y * ((size_t)M * N);

    int t = threadIdx.x;
    int w = t >> 6, l = t & 63, lrow = l & 15, lhi = l >> 4;
    int wr = w >> 1, wc = w & 1;

    int srow = l >> 2;                               // staging row within 16-row group
    int scol = (((l & 3) ^ ((l >> 3) & 3)) << 3);    // pre-swizzled source chunk

    const u16* Ag = A + (size_t)(m0 + wr * 64) * K + kbase;  // this wave's A rows
    const u16* Bg = B + (size_t)(n0 + wc * 64) * K + kbase;  // this wave's B rows

    auto stage = [&](int b, int kt) {
        int k0 = kt << 5;
        u16* dst = &lds[w][b][0];
#pragma unroll
        for (int n = 0; n < 4; ++n)
            gld_lds16(Ag + (size_t)(n * 16 + srow) * K + k0 + scol,
                      dst + n * 512 + l * 8);
#pragma unroll
        for (int n = 0; n < 4; ++n)
            gld_lds16(Bg + (size_t)(n * 16 + srow) * K + k0 + scol,
                      dst + 2048 + n * 512 + l * 8);
    };

    f32x4 acc[4][4] = {};
    int NT = Ks >> 5;                 // 32 here; requires NT >= 4
    stage(0, 0); stage(1, 1); stage(2, 2);
    asm volatile("s_waitcnt vmcnt(16)" ::: "memory");   // tile 0 landed (per-wave)
    __builtin_amdgcn_sched_barrier(0);

    int cur = 0;
    for (int kt = 0; kt < NT; ++kt) {
        const u16* base = &lds[w][cur][0];
        bf16x8 af[4], bfr[4];
#pragma unroll
        for (int i = 0; i < 4; ++i) {
            int row = i * 16 + lrow;
            int swz = (lhi ^ ((lrow >> 1) & 3)) << 3;
            af[i]  = *(const bf16x8*)(base + row * 32 + swz);
            bfr[i] = *(const bf16x8*)(base + 2048 + row * 32 + swz);
        }
        // our reads of buf[cur] must complete before overwriting it below
        asm volatile("s_waitcnt lgkmcnt(0)" ::: "memory");
        __builtin_amdgcn_sched_barrier(0);
        if (kt + 3 < NT) stage(cur, kt + 3);
#pragma unroll
        for (int i = 0; i < 4; ++i)
#pragma unroll
            for (int j = 0; j < 4; ++j)
                acc[i][j] = MFMA16(af[i], bfr[j], acc[i][j]);
        // retire tile kt+1 (needed next iter); keep newer stages in flight
        if (kt + 3 < NT)      asm volatile("s_waitcnt vmcnt(16)" ::: "memory");
        else if (kt + 2 < NT) asm volatile("s_waitcnt vmcnt(8)"  ::: "memory");
        else if (kt + 1 < NT) asm volatile("s_waitcnt vmcnt(0)"  ::: "memory");
        __builtin_amdgcn_sched_barrier(0);
        cur = (cur == 2) ? 0 : cur + 1;
    }
#pragma unroll
    for (int i = 0; i < 4; ++i) {
#pragma unroll
        for (int j = 0; j < 4; ++j) {
            int crow = m0 + wr * 64 + i * 16 + lhi * 4;
            int ccol = n0 + wc * 64 + j * 16 + lrow;
            float* cp = Cs + (size_t)crow * N + ccol;
#pragma unroll
            for (int r2 = 0; r2 < 4; ++r2) cp[(size_t)r2 * N] = acc[i][j][r2];
        }
    }
}

// ---------------- qkv post: partial-add + RMSNorm + RoPE + cast + head-major ------
__global__ __launch_bounds__(256) void qkv_post(const float* __restrict__ qkv0,
                                                const float* __restrict__ qkv1,
                                                const float* __restrict__ qw,
                                                const float* __restrict__ kw,
                                                u16* __restrict__ qb,
                                                u16* __restrict__ kb,
                                                u16* __restrict__ vb) {
    const float C = 0.18033688011112042f;  // 0.125 * log2(e)
    int s = blockIdx.x;
    int t = threadIdx.x, w = t >> 6, lane = t & 63;
    const float* row0 = qkv0 + (size_t)s * 3072;
    const float* row1 = qkv1 + (size_t)s * 3072;
    int d2 = lane & 31;
    float inv = exp2f(-(float)d2 * (13.287712379549449f / 32.0f));
    float ang = (float)s * inv;
    float cs = cosf(ang), sn = sinf(ang);
    for (int h = w; h < 48; h += 4) {
        float v = row0[h * 64 + lane] + row1[h * 64 + lane];
        if (h < 40) {
            float ss = v * v;
#pragma unroll
            for (int m = 32; m; m >>= 1) ss += __shfl_xor(ss, m);
            float rms = rsqrtf(ss * (1.0f / 64.0f) + 1e-6f);
            float wgt = (h < 32) ? qw[lane] : kw[lane];
            v = v * rms * wgt;
            float part = __shfl_xor(v, 32);
            float rot = (lane < 32) ? -part : part;
            v = v * cs + rot * sn;
            if (h < 32)
                qb[((size_t)h * 2048 + s) * 64 + lane] = f2bf(v * C);
            else
                kb[((size_t)(h - 32) * 2048 + s) * 64 + lane] = f2bf(v);
        } else {
            vb[((size_t)(h - 40) * 2048 + s) * 64 + lane] = f2bf(v);
        }
    }
}

// ---------------- V transpose: vb[kv][s][d] -> vt[kv][d][s] ----------------
__global__ __launch_bounds__(256) void transpose_v(const u16* __restrict__ vb,
                                                   u16* __restrict__ vt) {
    int kv = blockIdx.y;
    int s0 = blockIdx.x * 256;
    __shared__ __align__(16) u16 tile[64][256];
    int t = threadIdx.x;
    int sl = t >> 3;
    int d0 = (t & 7) * 8;
#pragma unroll
    for (int j = 0; j < 8; ++j) {
        int s = sl + j * 32;
        u16x8 v = *(const u16x8*)(vb + ((size_t)kv * 2048 + s0 + s) * 64 + d0);
#pragma unroll
        for (int e = 0; e < 8; ++e) tile[d0 + e][s] = v[e];
    }
    __syncthreads();
    int d = t >> 2;
    int so = (t & 3) * 64;
#pragma unroll
    for (int j = 0; j < 8; ++j) {
        int s_local = so + j * 8;
        *(u16x8*)(vt + ((size_t)kv * 64 + d) * 2048 + s0 + s_local) =
            *(const u16x8*)&tile[d][s_local];
    }
}

// ---- flash attention v7: LDS-staged K/V shared by 4 waves, counted-vmcnt pipeline ----
__global__ __launch_bounds__(256) void attn_fa7(const u16* __restrict__ qb,
                                                const u16* __restrict__ kb,
                                                const u16* __restrict__ vt,
                                                u16* __restrict__ ab) {
    int qt = blockIdx.x, h = blockIdx.y, kv = h >> 2;
    int t = threadIdx.x, w = t >> 6, l = t & 63;
    int lq = l & 31, hi = l >> 5;
    int qlo_blk = qt * 128;
    int qlo = qlo_blk + w * 32;
    __shared__ __align__(16) u16 Kt[2][32 * 64];
    __shared__ __align__(16) u16 Vt[2][64 * 32];
    __shared__ u16 sm[4][32][66];

    const u16* qrow = qb + ((size_t)h * 2048 + qlo + lq) * 64 + hi * 8;
    bf16x8 qf[4];
#pragma unroll
    for (int dk = 0; dk < 4; ++dk) qf[dk] = *(const bf16x8*)(qrow + dk * 16);

    f32x16 oa = {}, ob = {};
    float lsum = 0.f;

    int ktA = (qlo_blk >= 512) ? ((qlo_blk >> 5) - 16) : 0;
    int ktB = (qlo_blk >> 5) + 3;
    const u16* kb_h = kb + (size_t)kv * 2048 * 64;
    const u16* vt_h = vt + (size_t)kv * 64 * 2048;

    int sk_row = t >> 3, sk_c = ((t & 7) ^ (sk_row & 7)) << 3;
    int sv_row = t >> 2, sv_c = (((t & 3) ^ ((t >> 3) & 3))) << 3;

    auto stage = [&](int buf, int kt) {
        int k0 = kt << 5;
        gld_lds16(kb_h + (size_t)(k0 + sk_row) * 64 + sk_c, &Kt[buf][t * 8]);
        gld_lds16(vt_h + (size_t)sv_row * 2048 + k0 + sv_c, &Vt[buf][t * 8]);
    };

    stage(0, ktA);
    int cur = 0;
    for (int kt = ktA; kt <= ktB; ++kt) {
        if (kt < ktB) {
            stage(cur ^ 1, kt + 1);
            asm volatile("s_waitcnt vmcnt(2)" ::: "memory");
        } else {
            asm volatile("s_waitcnt vmcnt(0)" ::: "memory");
        }
        asm volatile("s_barrier" ::: "memory");

        int k0 = kt << 5;
        bool active = (k0 <= qlo + 31) && (k0 >= qlo - 542);
        if (active) {
            bf16x8 kf[4], vaf[2], vbf[2];
#pragma unroll
            for (int c = 0; c < 4; ++c)
                kf[c] = *(const bf16x8*)&Kt[cur][lq * 64 + (((c * 2 + hi) ^ (lq & 7)) << 3)];
#pragma unroll
            for (int vi = 0; vi < 2; ++vi) {
                int swz = ((vi * 2 + hi) ^ ((lq >> 1) & 3)) << 3;
                vaf[vi] = *(const bf16x8*)&Vt[cur][lq * 32 + swz];
                vbf[vi] = *(const bf16x8*)&Vt[cur][(lq + 32) * 32 + swz];
            }
            asm volatile("s_waitcnt lgkmcnt(0)" ::: "memory");
            __builtin_amdgcn_sched_barrier(0);

            f32x16 s = {};
            s = MFMA32(kf[0], qf[0], s);
            s = MFMA32(kf[1], qf[1], s);
            s = MFMA32(kf[2], qf[2], s);
            s = MFMA32(kf[3], qf[3], s);

            bool edge = (k0 + 31 > qlo) || (qlo + 31 - k0 >= 512);
            if (edge) {
                int q = qlo + lq;
#pragma unroll
                for (int r = 0; r < 16; ++r) {
                    int k = k0 + (r & 3) + 8 * (r >> 2) + 4 * hi;
                    if (!((unsigned)(q - k) < 512u)) s[r] = -1e30f;
                }
            }
            float p[16];
#pragma unroll
            for (int r = 0; r < 16; ++r) {
                p[r] = exp2f(s[r]);
                lsum += p[r];
            }
            u32 pk0 = cvtpk(p[0], p[1]),   pk1 = cvtpk(p[2], p[3]);
            u32 pk2 = cvtpk(p[4], p[5]),   pk3 = cvtpk(p[6], p[7]);
            u32 pk4 = cvtpk(p[8], p[9]),   pk5 = cvtpk(p[10], p[11]);
            u32 pk6 = cvtpk(p[12], p[13]), pk7 = cvtpk(p[14], p[15]);
            u32x2 r02 = __builtin_amdgcn_permlane32_swap(pk0, pk2, false, false);
            u32x2 r13 = __builtin_amdgcn_permlane32_swap(pk1, pk3, false, false);
            u32x2 r46 = __builtin_amdgcn_permlane32_swap(pk4, pk6, false, false);
            u32x2 r57 = __builtin_amdgcn_permlane32_swap(pk5, pk7, false, false);
            bf16x8 b0, b1;
            {
                u32* bp = (u32*)&b0;
                bp[0] = r02[0]; bp[1] = r13[0]; bp[2] = r02[1]; bp[3] = r13[1];
                u32* bq = (u32*)&b1;
                bq[0] = r46[0]; bq[1] = r57[0]; bq[2] = r46[1]; bq[3] = r57[1];
            }
            oa = MFMA32(vaf[0], b0, oa);
            oa = MFMA32(vaf[1], b1, oa);
            ob = MFMA32(vbf[0], b0, ob);
            ob = MFMA32(vbf[1], b1, ob);
        }
        asm volatile("s_barrier" ::: "memory");
        cur ^= 1;
    }

    lsum += __shfl_xor(lsum, 32);
    float inv = 1.0f / lsum;
#pragma unroll
    for (int rp = 0; rp < 8; ++rp) {
        int r = rp * 2;
        int d = (r & 3) + 8 * (r >> 2) + 4 * hi;
        *(u32*)&sm[w][lq][d]      = cvtpk(oa[r] * inv, oa[r + 1] * inv);
        *(u32*)&sm[w][lq][d + 32] = cvtpk(ob[r] * inv, ob[r + 1] * inv);
    }
    asm volatile("s_waitcnt lgkmcnt(0)" ::: "memory");
    int qr = l >> 1, dbase = (l & 1) * 32;
    size_t orow = (size_t)(qlo + qr) * 2048 + h * 64 + dbase;
#pragma unroll
    for (int c2 = 0; c2 < 8; ++c2) {
        u32 w0 = *(const u32*)&sm[w][qr][dbase + c2 * 4];
        u32 w1 = *(const u32*)&sm[w][qr][dbase + c2 * 4 + 2];
        u32x2 val = { w0, w1 };
        *(u32x2*)(ab + orow + c2 * 4) = val;
    }
}

// ---------------- launch ----------------
extern "C" void kernel_launch(void* const* d_in, const int* in_sizes, int n_in,
                              void* d_out, int out_size, void* d_ws, size_t ws_size,
                              hipStream_t stream) {
    const float* x     = (const float*)d_in[0];
    const float* w_qkv = (const float*)d_in[1];
    const float* w_out = (const float*)d_in[2];
    const float* qw    = (const float*)d_in[3];
    const float* kw    = (const float*)d_in[4];
    float* out = (float*)d_out;

    char* ws = (char*)d_ws;
    u16*   x_b    = (u16*)(ws);
    u16*   wB     = (u16*)(ws + 8388608);
    u16*   q_b    = (u16*)(ws);
    u16*   k_b    = (u16*)(ws + 8388608);
    u16*   v_b    = (u16*)(ws + 10485760);
    u16*   v_t    = (u16*)(ws + 12582912);
    float* P0     = (float*)(ws + 20971520);
    float* O0     = (float*)(ws + 20971520);
    float* O1     = (float*)(ws + 37748736);
    u16*   attn_b = (u16*)(ws + 54525952);

    cvt_bf16<<<2048, 256, 0, stream>>>(x, x_b, 2048 * 2048 / 4);
    cvt_bf16<<<2048, 256, 0, stream>>>(w_qkv, wB, 3072 * 2048 / 4);
    gemm_bt<2><<<dim3(384, 2), 256, 0, stream>>>(x_b, wB, P0, 2048, 3072, 2048);
    qkv_post<<<2048, 256, 0, stream>>>(P0, P0 + (size_t)2048 * 3072, qw, kw, q_b, k_b, v_b);
    transpose_v<<<dim3(8, 8), 256, 0, stream>>>(v_b, v_t);
    attn_fa7<<<dim3(16, 32), 256, 0, stream>>>(q_b, k_b, v_t, attn_b);
    cvt_bf16<<<2048, 256, 0, stream>>>(w_out, wB, 2048 * 2048 / 4);
    gemm_bt<2><<<dim3(256, 2), 256, 0, stream>>>(attn_b, wB, O0, 2048, 2048, 2048);
    reduce_add<<<1024, 256, 0, stream>>>((const float4*)O0, (const float4*)O1,
                                         (float4*)out, 2048 * 2048 / 4);
}

// Round 13
// 140.787 us; speedup vs baseline: 1.1235x; 1.1235x over previous
//
#include <hip/hip_runtime.h>

typedef unsigned short u16;
typedef unsigned int u32;
typedef __bf16 bf16x8 __attribute__((ext_vector_type(8)));
typedef float f32x4 __attribute__((ext_vector_type(4)));
typedef float f32x16 __attribute__((ext_vector_type(16)));
typedef u16 u16x8 __attribute__((ext_vector_type(8)));
typedef u32 u32x2 __attribute__((ext_vector_type(2)));
typedef u32 u32x4 __attribute__((ext_vector_type(4)));

#define MFMA16(a, b, c) __builtin_amdgcn_mfma_f32_16x16x32_bf16((a), (b), (c), 0, 0, 0)
#define MFMA32(a, b, c) __builtin_amdgcn_mfma_f32_32x32x16_bf16((a), (b), (c), 0, 0, 0)

__device__ __forceinline__ u16 f2bf(float f) {
    unsigned int u = __float_as_uint(f);
    u = (u + 0x7FFF + ((u >> 16) & 1)) >> 16;
    return (u16)u;
}

__device__ __forceinline__ u32 cvtpk(float a, float b) {
    u32 d;
    asm("v_cvt_pk_bf16_f32 %0, %1, %2" : "=v"(d) : "v"(a), "v"(b));
    return d;
}

__device__ __forceinline__ void gld_lds16(const u16* g, u16* l) {
    __builtin_amdgcn_global_load_lds(
        (const __attribute__((address_space(1))) unsigned int*)g,
        (__attribute__((address_space(3))) unsigned int*)l, 16, 0, 0);
}

// ---------------- fp32 -> bf16 cast ----------------
__global__ __launch_bounds__(256) void cvt_bf16(const float* __restrict__ in,
                                                u16* __restrict__ out, int n4) {
    int idx = blockIdx.x * blockDim.x + threadIdx.x;
    int stride = gridDim.x * blockDim.x;
    for (int i = idx; i < n4; i += stride) {
        float4 v = reinterpret_cast<const float4*>(in)[i];
        ushort4 o;
        o.x = f2bf(v.x); o.y = f2bf(v.y); o.z = f2bf(v.z); o.w = f2bf(v.w);
        reinterpret_cast<ushort4*>(out)[i] = o;
    }
}

// ---------------- partial-sum reduce: o = a + b ----------------
__global__ __launch_bounds__(256) void reduce_add(const float4* __restrict__ a,
                                                  const float4* __restrict__ b,
                                                  float4* __restrict__ o, int n4) {
    int idx = blockIdx.x * blockDim.x + threadIdx.x;
    int stride = gridDim.x * blockDim.x;
    for (int i = idx; i < n4; i += stride) {
        float4 va = a[i], vb = b[i];
        float4 vo = {va.x + vb.x, va.y + vb.y, va.z + vb.z, va.w + vb.w};
        o[i] = vo;
    }
}

// ---- bf16 GEMM: r11 body (4 waves, depth-3, T2 swizzle, conflicts=0) +
// 2D-chunked XCD rectangle mapping: each XCD owns an RMxRN tile rectangle so its
// co-resident blocks share A/B panels inside the 4MB per-XCD L2 (HK chunked T1).
// Grid of tile-rectangles: XN rects along N, (8/XN) along M; rect id = bid&7.
template <int SPLITK, int RM, int RN, int XN>
__global__ __launch_bounds__(256) void gemm_bt(const u16* __restrict__ A,
                                               const u16* __restrict__ B,
                                               float* __restrict__ C,
                                               int M, int N, int K) {
    __shared__ __align__(16) u16 As[3][128 * 32];
    __shared__ __align__(16) u16 Bs[3][128 * 32];

    int bid = blockIdx.x;
    int xcd = bid & 7;
    int r = bid >> 3;
    int tm = (xcd / XN) * RM + (r / RN);
    int tn = (xcd % XN) * RN + (r % RN);
    int m0 = tm << 7, n0 = tn << 7;

    int Ks = K / SPLITK;
    int kbase = blockIdx.y * Ks;
    float* Cs = C + (size_t)blockIdx.y * ((size_t)M * N);

    int t = threadIdx.x;
    int w = t >> 6, l = t & 63, lrow = l & 15, lhi = l >> 4;
    int wr = w >> 1, wc = w & 1;

    int e0 = t * 8;
    int row0 = t >> 2;                                   // staging row (0..63)
    int col0 = (((t & 3) ^ ((t >> 3) & 3)) << 3);        // pre-swizzled source chunk

    const u16* Ag = A + (size_t)m0 * K + kbase;
    const u16* Bg = B + (size_t)n0 * K + kbase;

    auto stage = [&](int sbuf, int kt) {
        int k0 = kt << 5;
        gld_lds16(Ag + (size_t)row0 * K + k0 + col0, &As[sbuf][e0]);
        gld_lds16(Ag + (size_t)(row0 + 64) * K + k0 + col0, &As[sbuf][e0 + 2048]);
        gld_lds16(Bg + (size_t)row0 * K + k0 + col0, &Bs[sbuf][e0]);
        gld_lds16(Bg + (size_t)(row0 + 64) * K + k0 + col0, &Bs[sbuf][e0 + 2048]);
    };

    f32x4 acc[4][4] = {};
    int NT = Ks >> 5;
    stage(0, 0); stage(1, 1); stage(2, 2);
    asm volatile("s_waitcnt vmcnt(8)" ::: "memory");     // tile 0 landed
    asm volatile("s_barrier" ::: "memory");
    int cur = 0;
    for (int kt = 0; kt < NT; ++kt) {
        bf16x8 af[4], bfr[4];
#pragma unroll
        for (int i = 0; i < 4; ++i) {
            int row = wr * 64 + i * 16 + lrow;
            af[i] = *(const bf16x8*)&As[cur][row * 32 + ((lhi ^ ((row >> 1) & 3)) << 3)];
        }
#pragma unroll
        for (int j = 0; j < 4; ++j) {
            int row = wc * 64 + j * 16 + lrow;
            bfr[j] = *(const bf16x8*)&Bs[cur][row * 32 + ((lhi ^ ((row >> 1) & 3)) << 3)];
        }
        asm volatile("s_waitcnt lgkmcnt(0)" ::: "memory");
        __builtin_amdgcn_sched_barrier(0);
        asm volatile("s_barrier" ::: "memory");          // all waves done reading cur
        if (kt + 3 < NT) stage(cur, kt + 3);             // reuse cur for tile t+3
#pragma unroll
        for (int i = 0; i < 4; ++i)
#pragma unroll
            for (int j = 0; j < 4; ++j)
                acc[i][j] = MFMA16(af[i], bfr[j], acc[i][j]);
        if (kt + 1 < NT) {
            if (kt + 3 < NT)      asm volatile("s_waitcnt vmcnt(8)" ::: "memory");
            else if (kt + 2 < NT) asm volatile("s_waitcnt vmcnt(4)" ::: "memory");
            else                  asm volatile("s_waitcnt vmcnt(0)" ::: "memory");
            asm volatile("s_barrier" ::: "memory");
        }
        cur = (cur == 2) ? 0 : cur + 1;
    }
#pragma unroll
    for (int i = 0; i < 4; ++i) {
#pragma unroll
        for (int j = 0; j < 4; ++j) {
            int crow = m0 + wr * 64 + i * 16 + lhi * 4;
            int ccol = n0 + wc * 64 + j * 16 + lrow;
            float* cp = Cs + (size_t)crow * N + ccol;
#pragma unroll
            for (int r2 = 0; r2 < 4; ++r2) cp[(size_t)r2 * N] = acc[i][j][r2];
        }
    }
}

// ---------------- qkv post: partial-add + RMSNorm + RoPE + cast + head-major ------
__global__ __launch_bounds__(256) void qkv_post(const float* __restrict__ qkv0,
                                                const float* __restrict__ qkv1,
                                                const float* __restrict__ qw,
                                                const float* __restrict__ kw,
                                                u16* __restrict__ qb,
                                                u16* __restrict__ kb,
                                                u16* __restrict__ vb) {
    const float C = 0.18033688011112042f;  // 0.125 * log2(e)
    int s = blockIdx.x;
    int t = threadIdx.x, w = t >> 6, lane = t & 63;
    const float* row0 = qkv0 + (size_t)s * 3072;
    const float* row1 = qkv1 + (size_t)s * 3072;
    int d2 = lane & 31;
    float inv = exp2f(-(float)d2 * (13.287712379549449f / 32.0f));
    float ang = (float)s * inv;
    float cs = cosf(ang), sn = sinf(ang);
    for (int h = w; h < 48; h += 4) {
        float v = row0[h * 64 + lane] + row1[h * 64 + lane];
        if (h < 40) {
            float ss = v * v;
#pragma unroll
            for (int m = 32; m; m >>= 1) ss += __shfl_xor(ss, m);
            float rms = rsqrtf(ss * (1.0f / 64.0f) + 1e-6f);
            float wgt = (h < 32) ? qw[lane] : kw[lane];
            v = v * rms * wgt;
            float part = __shfl_xor(v, 32);
            float rot = (lane < 32) ? -part : part;
            v = v * cs + rot * sn;
            if (h < 32)
                qb[((size_t)h * 2048 + s) * 64 + lane] = f2bf(v * C);
            else
                kb[((size_t)(h - 32) * 2048 + s) * 64 + lane] = f2bf(v);
        } else {
            vb[((size_t)(h - 40) * 2048 + s) * 64 + lane] = f2bf(v);
        }
    }
}

// ---------------- V transpose: vb[kv][s][d] -> vt[kv][d][s] ----------------
__global__ __launch_bounds__(256) void transpose_v(const u16* __restrict__ vb,
                                                   u16* __restrict__ vt) {
    int kv = blockIdx.y;
    int s0 = blockIdx.x * 256;
    __shared__ __align__(16) u16 tile[64][256];
    int t = threadIdx.x;
    int sl = t >> 3;
    int d0 = (t & 7) * 8;
#pragma unroll
    for (int j = 0; j < 8; ++j) {
        int s = sl + j * 32;
        u16x8 v = *(const u16x8*)(vb + ((size_t)kv * 2048 + s0 + s) * 64 + d0);
#pragma unroll
        for (int e = 0; e < 8; ++e) tile[d0 + e][s] = v[e];
    }
    __syncthreads();
    int d = t >> 2;
    int so = (t & 3) * 64;
#pragma unroll
    for (int j = 0; j < 8; ++j) {
        int s_local = so + j * 8;
        *(u16x8*)(vt + ((size_t)kv * 64 + d) * 2048 + s0 + s_local) =
            *(const u16x8*)&tile[d][s_local];
    }
}

// ---- flash attention v7: LDS-staged K/V shared by 4 waves, counted-vmcnt pipeline ----
__global__ __launch_bounds__(256) void attn_fa7(const u16* __restrict__ qb,
                                                const u16* __restrict__ kb,
                                                const u16* __restrict__ vt,
                                                u16* __restrict__ ab) {
    int qt = blockIdx.x, h = blockIdx.y, kv = h >> 2;
    int t = threadIdx.x, w = t >> 6, l = t & 63;
    int lq = l & 31, hi = l >> 5;
    int qlo_blk = qt * 128;
    int qlo = qlo_blk + w * 32;
    __shared__ __align__(16) u16 Kt[2][32 * 64];
    __shared__ __align__(16) u16 Vt[2][64 * 32];
    __shared__ u16 sm[4][32][66];

    const u16* qrow = qb + ((size_t)h * 2048 + qlo + lq) * 64 + hi * 8;
    bf16x8 qf[4];
#pragma unroll
    for (int dk = 0; dk < 4; ++dk) qf[dk] = *(const bf16x8*)(qrow + dk * 16);

    f32x16 oa = {}, ob = {};
    float lsum = 0.f;

    int ktA = (qlo_blk >= 512) ? ((qlo_blk >> 5) - 16) : 0;
    int ktB = (qlo_blk >> 5) + 3;
    const u16* kb_h = kb + (size_t)kv * 2048 * 64;
    const u16* vt_h = vt + (size_t)kv * 64 * 2048;

    int sk_row = t >> 3, sk_c = ((t & 7) ^ (sk_row & 7)) << 3;
    int sv_row = t >> 2, sv_c = (((t & 3) ^ ((t >> 3) & 3))) << 3;

    auto stage = [&](int buf, int kt) {
        int k0 = kt << 5;
        gld_lds16(kb_h + (size_t)(k0 + sk_row) * 64 + sk_c, &Kt[buf][t * 8]);
        gld_lds16(vt_h + (size_t)sv_row * 2048 + k0 + sv_c, &Vt[buf][t * 8]);
    };

    stage(0, ktA);
    int cur = 0;
    for (int kt = ktA; kt <= ktB; ++kt) {
        if (kt < ktB) {
            stage(cur ^ 1, kt + 1);
            asm volatile("s_waitcnt vmcnt(2)" ::: "memory");
        } else {
            asm volatile("s_waitcnt vmcnt(0)" ::: "memory");
        }
        asm volatile("s_barrier" ::: "memory");

        int k0 = kt << 5;
        bool active = (k0 <= qlo + 31) && (k0 >= qlo - 542);
        if (active) {
            bf16x8 kf[4], vaf[2], vbf[2];
#pragma unroll
            for (int c = 0; c < 4; ++c)
                kf[c] = *(const bf16x8*)&Kt[cur][lq * 64 + (((c * 2 + hi) ^ (lq & 7)) << 3)];
#pragma unroll
            for (int vi = 0; vi < 2; ++vi) {
                int swz = ((vi * 2 + hi) ^ ((lq >> 1) & 3)) << 3;
                vaf[vi] = *(const bf16x8*)&Vt[cur][lq * 32 + swz];
                vbf[vi] = *(const bf16x8*)&Vt[cur][(lq + 32) * 32 + swz];
            }
            asm volatile("s_waitcnt lgkmcnt(0)" ::: "memory");
            __builtin_amdgcn_sched_barrier(0);

            f32x16 s = {};
            s = MFMA32(kf[0], qf[0], s);
            s = MFMA32(kf[1], qf[1], s);
            s = MFMA32(kf[2], qf[2], s);
            s = MFMA32(kf[3], qf[3], s);

            bool edge = (k0 + 31 > qlo) || (qlo + 31 - k0 >= 512);
            if (edge) {
                int q = qlo + lq;
#pragma unroll
                for (int r = 0; r < 16; ++r) {
                    int k = k0 + (r & 3) + 8 * (r >> 2) + 4 * hi;
                    if (!((unsigned)(q - k) < 512u)) s[r] = -1e30f;
                }
            }
            float p[16];
#pragma unroll
            for (int r = 0; r < 16; ++r) {
                p[r] = exp2f(s[r]);
                lsum += p[r];
            }
            u32 pk0 = cvtpk(p[0], p[1]),   pk1 = cvtpk(p[2], p[3]);
            u32 pk2 = cvtpk(p[4], p[5]),   pk3 = cvtpk(p[6], p[7]);
            u32 pk4 = cvtpk(p[8], p[9]),   pk5 = cvtpk(p[10], p[11]);
            u32 pk6 = cvtpk(p[12], p[13]), pk7 = cvtpk(p[14], p[15]);
            u32x2 r02 = __builtin_amdgcn_permlane32_swap(pk0, pk2, false, false);
            u32x2 r13 = __builtin_amdgcn_permlane32_swap(pk1, pk3, false, false);
            u32x2 r46 = __builtin_amdgcn_permlane32_swap(pk4, pk6, false, false);
            u32x2 r57 = __builtin_amdgcn_permlane32_swap(pk5, pk7, false, false);
            bf16x8 b0, b1;
            {
                u32* bp = (u32*)&b0;
                bp[0] = r02[0]; bp[1] = r13[0]; bp[2] = r02[1]; bp[3] = r13[1];
                u32* bq = (u32*)&b1;
                bq[0] = r46[0]; bq[1] = r57[0]; bq[2] = r46[1]; bq[3] = r57[1];
            }
            oa = MFMA32(vaf[0], b0, oa);
            oa = MFMA32(vaf[1], b1, oa);
            ob = MFMA32(vbf[0], b0, ob);
            ob = MFMA32(vbf[1], b1, ob);
        }
        asm volatile("s_barrier" ::: "memory");
        cur ^= 1;
    }

    lsum += __shfl_xor(lsum, 32);
    float inv = 1.0f / lsum;
#pragma unroll
    for (int rp = 0; rp < 8; ++rp) {
        int r = rp * 2;
        int d = (r & 3) + 8 * (r >> 2) + 4 * hi;
        *(u32*)&sm[w][lq][d]      = cvtpk(oa[r] * inv, oa[r + 1] * inv);
        *(u32*)&sm[w][lq][d + 32] = cvtpk(ob[r] * inv, ob[r + 1] * inv);
    }
    asm volatile("s_waitcnt lgkmcnt(0)" ::: "memory");
    int qr = l >> 1, dbase = (l & 1) * 32;
    size_t orow = (size_t)(qlo + qr) * 2048 + h * 64 + dbase;
#pragma unroll
    for (int c2 = 0; c2 < 8; ++c2) {
        u32 w0 = *(const u32*)&sm[w][qr][dbase + c2 * 4];
        u32 w1 = *(const u32*)&sm[w][qr][dbase + c2 * 4 + 2];
        u32x2 val = { w0, w1 };
        *(u32x2*)(ab + orow + c2 * 4) = val;
    }
}

// ---------------- launch ----------------
extern "C" void kernel_launch(void* const* d_in, const int* in_sizes, int n_in,
                              void* d_out, int out_size, void* d_ws, size_t ws_size,
                              hipStream_t stream) {
    const float* x     = (const float*)d_in[0];
    const float* w_qkv = (const float*)d_in[1];
    const float* w_out = (const float*)d_in[2];
    const float* qw    = (const float*)d_in[3];
    const float* kw    = (const float*)d_in[4];
    float* out = (float*)d_out;

    char* ws = (char*)d_ws;
    u16*   x_b    = (u16*)(ws);
    u16*   wB     = (u16*)(ws + 8388608);
    u16*   q_b    = (u16*)(ws);
    u16*   k_b    = (u16*)(ws + 8388608);
    u16*   v_b    = (u16*)(ws + 10485760);
    u16*   v_t    = (u16*)(ws + 12582912);
    float* P0     = (float*)(ws + 20971520);
    float* O0     = (float*)(ws + 20971520);
    float* O1     = (float*)(ws + 37748736);
    u16*   attn_b = (u16*)(ws + 54525952);

    cvt_bf16<<<2048, 256, 0, stream>>>(x, x_b, 2048 * 2048 / 4);
    cvt_bf16<<<2048, 256, 0, stream>>>(w_qkv, wB, 3072 * 2048 / 4);
    // gemm1: 16x24 tile grid -> 8 XCD rectangles of 8(M)x6(N), XN=4 rect-cols
    gemm_bt<2, 8, 6, 4><<<dim3(384, 2), 256, 0, stream>>>(x_b, wB, P0, 2048, 3072, 2048);
    qkv_post<<<2048, 256, 0, stream>>>(P0, P0 + (size_t)2048 * 3072, qw, kw, q_b, k_b, v_b);
    transpose_v<<<dim3(8, 8), 256, 0, stream>>>(v_b, v_t);
    attn_fa7<<<dim3(16, 32), 256, 0, stream>>>(q_b, k_b, v_t, attn_b);
    cvt_bf16<<<2048, 256, 0, stream>>>(w_out, wB, 2048 * 2048 / 4);
    // gemm2: 16x16 tile grid -> 8 XCD rectangles of 4(M)x8(N), XN=2 rect-cols
    gemm_bt<2, 4, 8, 2><<<dim3(256, 2), 256, 0, stream>>>(attn_b, wB, O0, 2048, 2048, 2048);
    reduce_add<<<1024, 256, 0, stream>>>((const float4*)O0, (const float4*)O1,
                                         (float4*)out, 2048 * 2048 / 4);
}